// Round 11
// baseline (1319.939 us; speedup 1.0000x reference)
//
#include <hip/hip_runtime.h>
#include <cstdint>
#include <cstddef>
#include <math.h>

// Problem dims (fixed)
#define LL  8
#define BB  2
#define SS  1024
#define DD  1024
#define HH  16
#define HD  64
#define FFD 4096
#define BSD (BB*SS*DD)   // 2,097,152

typedef __attribute__((ext_vector_type(4))) float f32x4;
typedef __attribute__((ext_vector_type(8))) short bf16x8;
typedef __attribute__((ext_vector_type(4))) short bf16x4;

__device__ __forceinline__ unsigned short f2bf(float f) {
    unsigned u = __float_as_uint(f);
    unsigned r = (u + 0x7fffu + ((u >> 16) & 1u)) >> 16;   // RTN-even
    return (unsigned short)r;
}
__device__ __forceinline__ float bf2f(unsigned short u) {
    return __uint_as_float((unsigned)u << 16);
}

#define GLD16(gsrc, ldst) \
    __builtin_amdgcn_global_load_lds((const __attribute__((address_space(1))) void*)(gsrc), \
                                     (__attribute__((address_space(3))) void*)(ldst), 16, 0, 0)

// XCD-aware bijective swizzle of the flattened xy block index (nwg % 8 == 0).
__device__ __forceinline__ void xcd_swizzle(int& bx, int& by)
{
    const int nx  = gridDim.x;
    const int nwg = nx * gridDim.y;
    const int flat = by * nx + bx;
    const int cpx = nwg >> 3;                 // chunks per XCD
    const int swz = (flat & 7) * cpx + (flat >> 3);
    bx = swz % nx;
    by = swz / nx;
}

// ---------------------------------------------------------------------------
// f32 -> bf16 elementwise convert (4 elems/thread)
// ---------------------------------------------------------------------------
__global__ __launch_bounds__(256)
void cvt_bf16(const float* __restrict__ in, unsigned short* __restrict__ out)
{
    size_t i = (size_t)blockIdx.x * 256 + threadIdx.x;
    float4 v = *(const float4*)(in + i * 4);
    ushort4 o;
    o.x = f2bf(v.x); o.y = f2bf(v.y); o.z = f2bf(v.z); o.w = f2bf(v.w);
    *(ushort4*)(out + i * 4) = o;
}

// x_in -> xbuf (f32 copy) + xb16 (bf16 copy), one pass
__global__ __launch_bounds__(256)
void cvt_x(const float* __restrict__ in, float* __restrict__ outf,
           unsigned short* __restrict__ outb)
{
    size_t i = (size_t)blockIdx.x * 256 + threadIdx.x;
    float4 v = *(const float4*)(in + i * 4);
    *(float4*)(outf + i * 4) = v;
    ushort4 o;
    o.x = f2bf(v.x); o.y = f2bf(v.y); o.z = f2bf(v.z); o.w = f2bf(v.w);
    *(ushort4*)(outb + i * 4) = o;
}

// ---------------------------------------------------------------------------
// bf16 MFMA GEMM, 256x128 tile (R11: bigger tile cuts staging bytes/FLOP by
// 26% and halves W re-fetch), BK=64 double-buffered, counted vmcnt, T2 XOR
// swizzle, T1 XCD swizzle. 512 thr = 8 waves (2Mx4N); wave = 128x32 out
// (8x2 frags of 16x16x32). LDS 96 KB -> 1 block/CU.
// Staging: 6 GLD16/thread/K-tile (A rows sr+{0,64,128,192}, W rows sr+{0,64}).
// vmcnt ledger: prologue 12 in flight; steady vmcnt(6); final iter vmcnt(0).
// mode 1: relu -> bf16 Cb      mode 2: QKV split (q bf16 / k,v f32+bf16)
// mode 3: bf16 partial -> Cb + z*M*N (split-K; LN fuses combine+bias)
// ---------------------------------------------------------------------------
__global__ __launch_bounds__(512)
void gemm_bf16(const unsigned short* __restrict__ A, const unsigned short* __restrict__ W,
               const float* __restrict__ bias,
               float* __restrict__ C, unsigned short* __restrict__ Cb,
               float* __restrict__ Ck, float* __restrict__ Cv,
               unsigned short* __restrict__ Kb16, unsigned short* __restrict__ Vb16,
               int M, int N, int klen, int mode)
{
    __shared__ unsigned short lds[2][(256 + 128) * 64];   // [dbuf][A(16384) | W(8192)]

    int bx = blockIdx.x, by = blockIdx.y;
    xcd_swizzle(bx, by);

    const int tid  = threadIdx.x;
    const int m0   = by * 256;
    const int n0   = bx * 128;
    const int kbase= blockIdx.z * klen;
    const int lane = tid & 63;
    const int w    = tid >> 6;          // 0..7
    const int wrM  = w >> 2;            // 0..1 (M half: 128 rows)
    const int wcN  = w & 3;             // 0..3 (N quarter: 32 cols)
    const int lr   = lane & 15;
    const int kq   = lane >> 4;

    const int K = (mode == 3) ? (klen * gridDim.z) : klen;   // row stride of A/W
    const int T = klen >> 6;                                  // # BK=64 tiles

    // Staging geometry: sr = tid>>3 (0..63), spc = tid&7; rows sr+i*64.
    // (sr + i*64)&7 == sr&7, so one swizzled column chunk serves all i.
    const int sr  = tid >> 3;
    const int spc = tid & 7;
    const int slc = spc ^ (sr & 7);    // logical (global) col chunk

    #define STAGE_TILE(ti, dst)                                                        \
        do {                                                                           \
            const int kc = kbase + (ti) * 64;                                          \
            GLD16(A + (size_t)(m0 + sr      ) * K + kc + slc * 8, (dst) + tid * 8);    \
            GLD16(A + (size_t)(m0 + sr +  64) * K + kc + slc * 8, (dst) + (tid + 512) * 8); \
            GLD16(A + (size_t)(m0 + sr + 128) * K + kc + slc * 8, (dst) + (tid + 1024) * 8); \
            GLD16(A + (size_t)(m0 + sr + 192) * K + kc + slc * 8, (dst) + (tid + 1536) * 8); \
            GLD16(W + (size_t)(n0 + sr      ) * K + kc + slc * 8, (dst) + 16384 + tid * 8);  \
            GLD16(W + (size_t)(n0 + sr +  64) * K + kc + slc * 8, (dst) + 16384 + (tid + 512) * 8); \
        } while (0)

    f32x4 acc[8][2];
    #pragma unroll
    for (int i = 0; i < 8; ++i)
        #pragma unroll
        for (int j = 0; j < 2; ++j) {
            f32x4 z = {0.f, 0.f, 0.f, 0.f};
            acc[i][j] = z;
        }

    // Prologue: stage tiles 0 and 1 (12 loads outstanding)
    STAGE_TILE(0, lds[0]);
    STAGE_TILE(1, lds[1]);

    for (int t = 0; t < T; ++t) {
        unsigned short* cb = lds[t & 1];

        if (t == T - 1) {
            // final tile: nothing behind it -> full drain (R6 lesson)
            asm volatile("s_waitcnt vmcnt(0)\n\ts_barrier" ::: "memory");
        } else {
            // tile t's 6 loads landed; tile t+1's 6 remain in flight
            asm volatile("s_waitcnt vmcnt(6)\n\ts_barrier" ::: "memory");
        }

        #pragma unroll
        for (int kk = 0; kk < 2; ++kk) {
            bf16x8 a[8], b[2];
            #pragma unroll
            for (int mf = 0; mf < 8; ++mf) {
                const int r = wrM * 128 + mf * 16 + lr;
                const int pc = (kk * 4 + kq) ^ (r & 7);
                a[mf] = *(const bf16x8*)(cb + r * 64 + pc * 8);
            }
            #pragma unroll
            for (int nf = 0; nf < 2; ++nf) {
                const int r = wcN * 32 + nf * 16 + lr;
                const int pc = (kk * 4 + kq) ^ (r & 7);
                b[nf] = *(const bf16x8*)(cb + 16384 + r * 64 + pc * 8);
            }
            __builtin_amdgcn_s_setprio(1);
            #pragma unroll
            for (int mf = 0; mf < 8; ++mf)
                #pragma unroll
                for (int nf = 0; nf < 2; ++nf)
                    acc[mf][nf] = __builtin_amdgcn_mfma_f32_16x16x32_bf16(
                        a[mf], b[nf], acc[mf][nf], 0, 0, 0);
            __builtin_amdgcn_s_setprio(0);
        }

        // all waves' reads of this buffer consumed -> safe to overwrite
        asm volatile("s_waitcnt lgkmcnt(0)\n\ts_barrier" ::: "memory");
        if (t + 2 < T) STAGE_TILE(t + 2, cb);
    }
    #undef STAGE_TILE

    // Epilogue. C/D layout: col = lane&15, row = (lane>>4)*4 + reg
    const int seg = n0 >> 10;
    #pragma unroll
    for (int nf = 0; nf < 2; ++nf) {
        const int cl = wcN * 32 + nf * 16 + lr;
        const float bv = (mode == 3) ? 0.f : bias[n0 + cl];
        #pragma unroll
        for (int mf = 0; mf < 8; ++mf) {
            #pragma unroll
            for (int r = 0; r < 4; ++r) {
                const int row = m0 + wrM * 128 + mf * 16 + kq * 4 + r;
                const float val = acc[mf][nf][r] + bv;
                if (mode == 2) {
                    const int col = (n0 & 1023) + cl;
                    float* dstf = (seg == 1) ? Ck : ((seg == 2) ? Cv : nullptr);
                    unsigned short* dstb = (seg == 0) ? Cb : ((seg == 1) ? Kb16 : Vb16);
                    if (dstf) dstf[(size_t)row * DD + col] = val;
                    dstb[(size_t)row * DD + col] = f2bf(val);
                } else if (mode == 1) {
                    Cb[(size_t)row * N + n0 + cl] = f2bf(fmaxf(val, 0.f));
                } else {   // mode 3: bf16 partial
                    Cb[(size_t)blockIdx.z * M * N + (size_t)row * N + n0 + cl] = f2bf(val);
                }
            }
        }
    }
}

// ---------------------------------------------------------------------------
// MFMA causal flash attention (unchanged from R9). Block = (128 q, h, b),
// 512 thr = 8 waves; KV-chunk 128; K[128][68], Vt[64][136], P[16][136].
// ---------------------------------------------------------------------------
__global__ __launch_bounds__(512)
void attn_mfma(const unsigned short* __restrict__ Qb, const unsigned short* __restrict__ Kb,
               const unsigned short* __restrict__ Vb, unsigned short* __restrict__ ctxb)
{
    int bx = blockIdx.x, by = blockIdx.y;
    xcd_swizzle(bx, by);
    const int qt = bx;              // q-tile 0..7 (128 rows each)
    const int h  = by;
    const int b  = blockIdx.z;
    const int tid  = threadIdx.x;
    const int lane = tid & 63;
    const int w    = tid >> 6;      // 0..7
    const int lr   = lane & 15;
    const int hi   = lane >> 4;

    __shared__ unsigned short smem[128 * 68 + 64 * 136 + 8 * 16 * 136];  // 69632 B
    unsigned short* Ks = smem;                                  // [128][68] key-major
    unsigned short* Vt = smem + 128 * 68;                       // [64][136] d-major
    unsigned short* Pl = smem + 128 * 68 + 64 * 136 + w * 16 * 136; // per-wave [16][136]

    const int qg0 = qt * 128 + w * 16;   // wave's first q row

    bf16x8 qa[2];
    {
        const unsigned short* qp = Qb + ((size_t)(b * SS + qg0 + lr)) * DD + h * HD;
        qa[0] = *(const bf16x8*)(qp + hi * 8);
        qa[1] = *(const bf16x8*)(qp + 32 + hi * 8);
    }

    f32x4 accO[4];
    #pragma unroll
    for (int t = 0; t < 4; ++t) { f32x4 z = {0.f,0.f,0.f,0.f}; accO[t] = z; }
    float m_run[4], l_run[4];
    #pragma unroll
    for (int r = 0; r < 4; ++r) { m_run[r] = -INFINITY; l_run[r] = 0.f; }

    const int nch = qt + 1;     // 128-key chunks
    for (int c = 0; c < nch; ++c) {
        __syncthreads();
        const unsigned short* kb = Kb + ((size_t)(b * SS + c * 128)) * DD + h * HD;
        const unsigned short* vb = Vb + ((size_t)(b * SS + c * 128)) * DD + h * HD;
        #pragma unroll
        for (int i = 0; i < 2; ++i) {
            int e = tid + i * 512;
            int r  = e >> 3, ch = e & 7;
            bf16x8 kv = *(const bf16x8*)(kb + (size_t)r * DD + ch * 8);
            *(bf16x4*)(Ks + r * 68 + ch * 8)     = __builtin_shufflevector(kv, kv, 0,1,2,3);
            *(bf16x4*)(Ks + r * 68 + ch * 8 + 4) = __builtin_shufflevector(kv, kv, 4,5,6,7);
            int k  = e & 127, d0 = (e >> 7) * 8;
            bf16x8 vv = *(const bf16x8*)(vb + (size_t)k * DD + d0);
            #pragma unroll
            for (int j = 0; j < 8; ++j)
                Vt[(d0 + j) * 136 + k] = (unsigned short)vv[j];
        }
        __syncthreads();

        // QK^T: 8 k-tiles of 16
        f32x4 sa[8];
        #pragma unroll
        for (int t = 0; t < 8; ++t) { f32x4 z = {0.f,0.f,0.f,0.f}; sa[t] = z; }
        #pragma unroll
        for (int t = 0; t < 8; ++t) {
            #pragma unroll
            for (int s = 0; s < 2; ++s) {
                const unsigned short* bp = Ks + (t * 16 + lr) * 68 + s * 32 + hi * 8;
                bf16x4 b0 = *(const bf16x4*)bp;
                bf16x4 b1 = *(const bf16x4*)(bp + 4);
                bf16x8 bb = __builtin_shufflevector(b0, b1, 0,1,2,3,4,5,6,7);
                sa[t] = __builtin_amdgcn_mfma_f32_16x16x32_bf16(qa[s], bb, sa[t], 0, 0, 0);
            }
        }
        #pragma unroll
        for (int t = 0; t < 8; ++t) {
            #pragma unroll
            for (int r = 0; r < 4; ++r) {
                const int kg = c * 128 + t * 16 + lr;
                const int qg = qg0 + hi * 4 + r;
                sa[t][r] = (kg > qg) ? -1e30f : sa[t][r] * 0.125f;
            }
        }
        #pragma unroll
        for (int r = 0; r < 4; ++r) {
            float mx = -INFINITY;
            #pragma unroll
            for (int t = 0; t < 8; ++t) mx = fmaxf(mx, sa[t][r]);
            mx = fmaxf(mx, __shfl_xor(mx, 1));
            mx = fmaxf(mx, __shfl_xor(mx, 2));
            mx = fmaxf(mx, __shfl_xor(mx, 4));
            mx = fmaxf(mx, __shfl_xor(mx, 8));
            const float mn = fmaxf(m_run[r], mx);
            float sum = 0.f;
            #pragma unroll
            for (int t = 0; t < 8; ++t) {
                float p = __expf(sa[t][r] - mn);
                sa[t][r] = p;
                sum += p;
            }
            sum += __shfl_xor(sum, 1);
            sum += __shfl_xor(sum, 2);
            sum += __shfl_xor(sum, 4);
            sum += __shfl_xor(sum, 8);
            const float sc = __expf(m_run[r] - mn);
            l_run[r] = l_run[r] * sc + sum;
            m_run[r] = mn;
            #pragma unroll
            for (int t = 0; t < 4; ++t) accO[t][r] *= sc;
        }
        #pragma unroll
        for (int t = 0; t < 8; ++t)
            #pragma unroll
            for (int r = 0; r < 4; ++r)
                Pl[(hi * 4 + r) * 136 + t * 16 + lr] = f2bf(sa[t][r]);

        #pragma unroll
        for (int s = 0; s < 4; ++s) {
            const unsigned short* ap = Pl + lr * 136 + s * 32 + hi * 8;
            bf16x4 a0 = *(const bf16x4*)ap;
            bf16x4 a1 = *(const bf16x4*)(ap + 4);
            bf16x8 aa = __builtin_shufflevector(a0, a1, 0,1,2,3,4,5,6,7);
            #pragma unroll
            for (int t = 0; t < 4; ++t) {
                const unsigned short* bp = Vt + (t * 16 + lr) * 136 + s * 32 + hi * 8;
                bf16x4 b0 = *(const bf16x4*)bp;
                bf16x4 b1 = *(const bf16x4*)(bp + 4);
                bf16x8 bb = __builtin_shufflevector(b0, b1, 0,1,2,3,4,5,6,7);
                accO[t] = __builtin_amdgcn_mfma_f32_16x16x32_bf16(aa, bb, accO[t], 0, 0, 0);
            }
        }
    }

    float inv[4];
    #pragma unroll
    for (int r = 0; r < 4; ++r) inv[r] = 1.f / l_run[r];

    __syncthreads();
    float* Of = (float*)smem;   // [128][68] f32 = 34816 B, overlays smem
    #pragma unroll
    for (int t = 0; t < 4; ++t)
        #pragma unroll
        for (int r = 0; r < 4; ++r)
            Of[(w * 16 + hi * 4 + r) * 68 + t * 16 + lr] = accO[t][r] * inv[r];
    __syncthreads();
    #pragma unroll
    for (int i = 0; i < 2; ++i) {
        int e = tid + i * 512;
        int r = e >> 3, ch = e & 7;
        const float* src = Of + r * 68 + ch * 8;
        float4 v0 = *(const float4*)(src);
        float4 v1 = *(const float4*)(src + 4);
        bf16x8 o;
        o[0] = (short)f2bf(v0.x); o[1] = (short)f2bf(v0.y);
        o[2] = (short)f2bf(v0.z); o[3] = (short)f2bf(v0.w);
        o[4] = (short)f2bf(v1.x); o[5] = (short)f2bf(v1.y);
        o[6] = (short)f2bf(v1.z); o[7] = (short)f2bf(v1.w);
        *(bf16x8*)(ctxb + ((size_t)(b * SS + qt * 128 + r)) * DD + h * HD + ch * 8) = o;
    }
}

// ---------------------------------------------------------------------------
// xo = LayerNorm(x + P0+P1+P2+P3 + bias) * w + b ; P = bf16 partials.
// xo may equal x (in-place) or point at d_out for the final LN.
// ---------------------------------------------------------------------------
__global__ __launch_bounds__(256)
void ln_kernel(const float* __restrict__ x, float* __restrict__ xo,
               const unsigned short* __restrict__ P,
               const float* __restrict__ bias,
               const float* __restrict__ w, const float* __restrict__ b,
               unsigned short* __restrict__ xb)
{
    const size_t PS = (size_t)BSD;   // partial stride
    const int row = blockIdx.x;
    const int t   = threadIdx.x;
    const int d0  = t * 4;
    const float* xr = x + (size_t)row * DD;
    float* xor_ = xo + (size_t)row * DD;
    unsigned short* xbr = xb + (size_t)row * DD;
    const size_t base = (size_t)row * DD + d0;

    float4 xv = *(const float4*)(xr + d0);
    float4 bv = *(const float4*)(bias + d0);
    float z[4] = {xv.x + bv.x, xv.y + bv.y, xv.z + bv.z, xv.w + bv.w};
    #pragma unroll
    for (int p = 0; p < 4; ++p) {
        ushort4 pv = *(const ushort4*)(P + base + p * PS);
        z[0] += bf2f(pv.x); z[1] += bf2f(pv.y); z[2] += bf2f(pv.z); z[3] += bf2f(pv.w);
    }
    float s = z[0] + z[1] + z[2] + z[3];
    float ss = z[0]*z[0] + z[1]*z[1] + z[2]*z[2] + z[3]*z[3];

    #pragma unroll
    for (int off = 32; off; off >>= 1) {
        s  += __shfl_down(s, off);
        ss += __shfl_down(ss, off);
    }
    __shared__ float sbuf[4], ssbuf[4];
    const int wave = t >> 6, lane = t & 63;
    if (lane == 0) { sbuf[wave] = s; ssbuf[wave] = ss; }
    __syncthreads();
    if (t == 0) {
        float S = 0.f, SSum = 0.f;
        #pragma unroll
        for (int i = 0; i < 4; ++i) { S += sbuf[i]; SSum += ssbuf[i]; }
        float mean = S * (1.f / 1024.f);
        float var  = SSum * (1.f / 1024.f) - mean * mean;
        sbuf[0]  = mean;
        ssbuf[0] = rsqrtf(var + 1e-5f);
    }
    __syncthreads();
    const float mean = sbuf[0], rstd = ssbuf[0];

    float4 wv = *(const float4*)(w + d0);
    float4 bb = *(const float4*)(b + d0);
    float o0 = (z[0] - mean) * rstd * wv.x + bb.x;
    float o1 = (z[1] - mean) * rstd * wv.y + bb.y;
    float o2 = (z[2] - mean) * rstd * wv.z + bb.z;
    float o3 = (z[3] - mean) * rstd * wv.w + bb.w;
    *(float4*)(xor_ + d0) = make_float4(o0, o1, o2, o3);
    ushort4 ob4;
    ob4.x = f2bf(o0); ob4.y = f2bf(o1); ob4.z = f2bf(o2); ob4.w = f2bf(o3);
    *(ushort4*)(xbr + d0) = ob4;
}

// ---------------------------------------------------------------------------
extern "C" void kernel_launch(void* const* d_in, const int* in_sizes, int n_in,
                              void* d_out, int out_size, void* d_ws, size_t ws_size,
                              hipStream_t stream)
{
    const float* x_in  = (const float*)d_in[0];
    const float* qkv_w = (const float*)d_in[2];
    const float* qkv_b = (const float*)d_in[3];
    const float* out_w = (const float*)d_in[4];
    const float* out_b = (const float*)d_in[5];
    const float* w1    = (const float*)d_in[6];
    const float* b1    = (const float*)d_in[7];
    const float* w2    = (const float*)d_in[8];
    const float* b2    = (const float*)d_in[9];
    const float* ln1w  = (const float*)d_in[10];
    const float* ln1b  = (const float*)d_in[11];
    const float* ln2w  = (const float*)d_in[12];
    const float* ln2b  = (const float*)d_in[13];

    float* out_x = (float*)d_out;                    // [B,S,D]
    float* out_k = out_x + (size_t)BSD;              // [L,B,S,D]
    float* out_v = out_k + (size_t)LL * BSD;         // [L,B,S,D]

    const size_t MEG = 1024 * 1024;
    float* ws = (float*)d_ws;
    float*          xbuf  = ws;                               // 2M f32 (8 MB)
    unsigned short* part16= (unsigned short*)(ws + 2 * MEG);  // 4 x 2M bf16 (16 MB)
    unsigned short* xb16  = (unsigned short*)(ws + 6 * MEG);  // 2M bf16
    unsigned short* ctxb  = (unsigned short*)(ws + 7 * MEG);  // 2M bf16
    unsigned short* hb16  = (unsigned short*)(ws + 8 * MEG);  // 8M bf16 (16 MB)
    unsigned short* qb16  = hb16;                             // aliases (disjoint lifetime)
    unsigned short* kb16  = hb16 + 2 * MEG;
    unsigned short* vb16  = hb16 + 4 * MEG;
    unsigned short* wAll  = (unsigned short*)(ws + 12 * MEG); // 96M bf16 (192 MB)

    unsigned short* qkvW = wAll;                     // 24M
    unsigned short* outW = wAll + 24 * MEG;          //  8M
    unsigned short* w1W  = wAll + 32 * MEG;          // 32M
    unsigned short* w2W  = wAll + 64 * MEG;          // 32M

    cvt_bf16<<<24 * MEG / 1024, 256, 0, stream>>>(qkv_w, qkvW);
    cvt_bf16<<< 8 * MEG / 1024, 256, 0, stream>>>(out_w, outW);
    cvt_bf16<<<32 * MEG / 1024, 256, 0, stream>>>(w1,    w1W);
    cvt_bf16<<<32 * MEG / 1024, 256, 0, stream>>>(w2,    w2W);
    cvt_x<<<BSD / 1024, 256, 0, stream>>>(x_in, xbuf, xb16);

    const int M = BB * SS;   // 2048

    for (int l = 0; l < LL; ++l) {
        const float* qb  = qkv_b + (size_t)l * 3 * DD;
        const float* ob  = out_b + (size_t)l * DD;
        const float* b1l = b1    + (size_t)l * FFD;
        const float* b2l = b2    + (size_t)l * DD;
        const unsigned short* qwl = qkvW + (size_t)l * 3 * DD * DD;
        const unsigned short* owl = outW + (size_t)l * DD * DD;
        const unsigned short* w1l = w1W  + (size_t)l * FFD * DD;
        const unsigned short* w2l = w2W  + (size_t)l * DD * FFD;
        float* kc = out_k + (size_t)l * BSD;
        float* vc = out_v + (size_t)l * BSD;

        // 1. QKV projection (full K): q/k/v bf16 + f32 caches
        gemm_bf16<<<dim3(3 * DD / 128, M / 256, 1), 512, 0, stream>>>(
            xb16, qwl, qb, nullptr, qb16, kc, vc, kb16, vb16, M, 3 * DD, DD, 2);

        // 2. MFMA causal attention -> bf16 ctx
        attn_mfma<<<dim3(SS / 128, HH, BB), 512, 0, stream>>>(qb16, kb16, vb16, ctxb);

        // 3. output projection, split-K x4 -> bf16 partials
        gemm_bf16<<<dim3(DD / 128, M / 256, 4), 512, 0, stream>>>(
            ctxb, owl, nullptr, nullptr, part16, nullptr, nullptr, nullptr, nullptr,
            M, DD, DD / 4, 3);

        // 4. x = LN(x + Σpart + ob)
        ln_kernel<<<M, 256, 0, stream>>>(xbuf, xbuf, part16, ob,
                                         ln1w + (size_t)l * DD, ln1b + (size_t)l * DD, xb16);

        // 5. h = relu(x @ w1^T + b1) -> bf16
        gemm_bf16<<<dim3(FFD / 128, M / 256, 1), 512, 0, stream>>>(
            xb16, w1l, b1l, nullptr, hb16, nullptr, nullptr, nullptr, nullptr,
            M, FFD, DD, 1);

        // 6. mlp = h @ w2^T, split-K x4 -> bf16 partials
        gemm_bf16<<<dim3(DD / 128, M / 256, 4), 512, 0, stream>>>(
            hb16, w2l, nullptr, nullptr, part16, nullptr, nullptr, nullptr, nullptr,
            M, DD, FFD / 4, 3);

        // 7. x = LN(x + Σpart + b2); last layer writes d_out directly
        float* xo = (l == LL - 1) ? out_x : xbuf;
        ln_kernel<<<M, 256, 0, stream>>>(xbuf, xo, part16, b2l,
                                         ln2w + (size_t)l * DD, ln2b + (size_t)l * DD, xb16);
    }
}

// Round 12
// 1243.077 us; speedup vs baseline: 1.0618x; 1.0618x over previous
//
#include <hip/hip_runtime.h>
#include <cstdint>
#include <cstddef>
#include <math.h>

// Problem dims (fixed)
#define LL  8
#define BB  2
#define SS  1024
#define DD  1024
#define HH  16
#define HD  64
#define FFD 4096
#define BSD (BB*SS*DD)   // 2,097,152

typedef __attribute__((ext_vector_type(4))) float f32x4;
typedef __attribute__((ext_vector_type(8))) short bf16x8;
typedef __attribute__((ext_vector_type(4))) short bf16x4;

__device__ __forceinline__ unsigned short f2bf(float f) {
    unsigned u = __float_as_uint(f);
    unsigned r = (u + 0x7fffu + ((u >> 16) & 1u)) >> 16;   // RTN-even
    return (unsigned short)r;
}
__device__ __forceinline__ float bf2f(unsigned short u) {
    return __uint_as_float((unsigned)u << 16);
}

#define GLD16(gsrc, ldst) \
    __builtin_amdgcn_global_load_lds((const __attribute__((address_space(1))) void*)(gsrc), \
                                     (__attribute__((address_space(3))) void*)(ldst), 16, 0, 0)

// XCD-aware bijective swizzle of the flattened xy block index (nwg % 8 == 0).
__device__ __forceinline__ void xcd_swizzle(int& bx, int& by)
{
    const int nx  = gridDim.x;
    const int nwg = nx * gridDim.y;
    const int flat = by * nx + bx;
    const int cpx = nwg >> 3;                 // chunks per XCD
    const int swz = (flat & 7) * cpx + (flat >> 3);
    bx = swz % nx;
    by = swz / nx;
}

// ---------------------------------------------------------------------------
// f32 -> bf16 elementwise convert (4 elems/thread)
// ---------------------------------------------------------------------------
__global__ __launch_bounds__(256)
void cvt_bf16(const float* __restrict__ in, unsigned short* __restrict__ out)
{
    size_t i = (size_t)blockIdx.x * 256 + threadIdx.x;
    float4 v = *(const float4*)(in + i * 4);
    ushort4 o;
    o.x = f2bf(v.x); o.y = f2bf(v.y); o.z = f2bf(v.z); o.w = f2bf(v.w);
    *(ushort4*)(out + i * 4) = o;
}

// x_in -> xbuf (f32 copy) + xb16 (bf16 copy), one pass
__global__ __launch_bounds__(256)
void cvt_x(const float* __restrict__ in, float* __restrict__ outf,
           unsigned short* __restrict__ outb)
{
    size_t i = (size_t)blockIdx.x * 256 + threadIdx.x;
    float4 v = *(const float4*)(in + i * 4);
    *(float4*)(outf + i * 4) = v;
    ushort4 o;
    o.x = f2bf(v.x); o.y = f2bf(v.y); o.z = f2bf(v.z); o.w = f2bf(v.w);
    *(ushort4*)(outb + i * 4) = o;
}

// ---------------------------------------------------------------------------
// bf16 MFMA GEMM (R10-exact revert: best measured config, 2 blocks/CU).
// 128x128 tile, BK=64 double-buffered, counted vmcnt (T3/T4), T2 XOR swizzle,
// T1 XCD swizzle. 512 thr = 8 waves (2Mx4N); wave = 64x32 out (4x2 frags).
// vmcnt ledger: prologue 8 in flight; steady vmcnt(4); final iter vmcnt(0).
// mode 1: relu -> bf16 Cb      mode 2: QKV split (q bf16 / k,v f32+bf16)
// mode 3: bf16 partial -> Cb + z*M*N (split-K; LN fuses combine+bias)
// ---------------------------------------------------------------------------
__global__ __launch_bounds__(512)
void gemm_bf16(const unsigned short* __restrict__ A, const unsigned short* __restrict__ W,
               const float* __restrict__ bias,
               float* __restrict__ C, unsigned short* __restrict__ Cb,
               float* __restrict__ Ck, float* __restrict__ Cv,
               unsigned short* __restrict__ Kb16, unsigned short* __restrict__ Vb16,
               int M, int N, int klen, int mode)
{
    __shared__ unsigned short lds[2][2 * 128 * 64];   // [dbuf][A(8192) | W(8192)]

    int bx = blockIdx.x, by = blockIdx.y;
    xcd_swizzle(bx, by);

    const int tid  = threadIdx.x;
    const int m0   = by * 128;
    const int n0   = bx * 128;
    const int kbase= blockIdx.z * klen;
    const int lane = tid & 63;
    const int w    = tid >> 6;          // 0..7
    const int wr   = w >> 2;            // 0..1 (M half)
    const int wc   = w & 3;             // 0..3 (N quarter)
    const int lr   = lane & 15;
    const int kq   = lane >> 4;

    const int K = (mode == 3) ? (klen * gridDim.z) : klen;   // row stride of A/W
    const int T = klen >> 6;                                  // # BK=64 tiles

    // Staging: chunk c = tid + i*512; row = c>>3, phys chunk pc = c&7,
    // logical col chunk lc = pc ^ (row&7) (XOR involution = read side).
    const int srow0 = tid >> 3;
    const int spc0  = tid & 7;
    const int slc0  = spc0 ^ (srow0 & 7);
    const int srow1 = (tid + 512) >> 3;
    const int spc1  = (tid + 512) & 7;
    const int slc1  = spc1 ^ (srow1 & 7);

    #define STAGE_TILE(ti, dst)                                                   \
        do {                                                                      \
            const int kc = kbase + (ti) * 64;                                     \
            GLD16(A + (size_t)(m0 + srow0) * K + kc + slc0 * 8, (dst) + tid * 8); \
            GLD16(A + (size_t)(m0 + srow1) * K + kc + slc1 * 8, (dst) + 4096 + tid * 8); \
            GLD16(W + (size_t)(n0 + srow0) * K + kc + slc0 * 8, (dst) + 8192 + tid * 8); \
            GLD16(W + (size_t)(n0 + srow1) * K + kc + slc1 * 8, (dst) + 12288 + tid * 8); \
        } while (0)

    f32x4 acc[4][2];
    #pragma unroll
    for (int i = 0; i < 4; ++i)
        #pragma unroll
        for (int j = 0; j < 2; ++j) {
            f32x4 z = {0.f, 0.f, 0.f, 0.f};
            acc[i][j] = z;
        }

    STAGE_TILE(0, lds[0]);
    STAGE_TILE(1, lds[1]);

    for (int t = 0; t < T; ++t) {
        unsigned short* cb = lds[t & 1];

        if (t == T - 1) {
            asm volatile("s_waitcnt vmcnt(0)\n\ts_barrier" ::: "memory");
        } else {
            asm volatile("s_waitcnt vmcnt(4)\n\ts_barrier" ::: "memory");
        }

        bf16x8 a[4], b[2], a2[4], b2[2];
        #pragma unroll
        for (int mf = 0; mf < 4; ++mf) {
            const int r = wr * 64 + mf * 16 + lr;
            const int pc = kq ^ (r & 7);
            a[mf] = *(const bf16x8*)(cb + r * 64 + pc * 8);
        }
        #pragma unroll
        for (int nf = 0; nf < 2; ++nf) {
            const int r = wc * 32 + nf * 16 + lr;
            const int pc = kq ^ (r & 7);
            b[nf] = *(const bf16x8*)(cb + 8192 + r * 64 + pc * 8);
        }
        #pragma unroll
        for (int mf = 0; mf < 4; ++mf) {
            const int r = wr * 64 + mf * 16 + lr;
            const int pc = (4 + kq) ^ (r & 7);
            a2[mf] = *(const bf16x8*)(cb + r * 64 + pc * 8);
        }
        #pragma unroll
        for (int nf = 0; nf < 2; ++nf) {
            const int r = wc * 32 + nf * 16 + lr;
            const int pc = (4 + kq) ^ (r & 7);
            b2[nf] = *(const bf16x8*)(cb + 8192 + r * 64 + pc * 8);
        }

        __builtin_amdgcn_s_setprio(1);
        #pragma unroll
        for (int mf = 0; mf < 4; ++mf)
            #pragma unroll
            for (int nf = 0; nf < 2; ++nf)
                acc[mf][nf] = __builtin_amdgcn_mfma_f32_16x16x32_bf16(
                    a[mf], b[nf], acc[mf][nf], 0, 0, 0);
        #pragma unroll
        for (int mf = 0; mf < 4; ++mf)
            #pragma unroll
            for (int nf = 0; nf < 2; ++nf)
                acc[mf][nf] = __builtin_amdgcn_mfma_f32_16x16x32_bf16(
                    a2[mf], b2[nf], acc[mf][nf], 0, 0, 0);
        __builtin_amdgcn_s_setprio(0);

        asm volatile("s_waitcnt lgkmcnt(0)\n\ts_barrier" ::: "memory");
        if (t + 2 < T) STAGE_TILE(t + 2, cb);
    }
    #undef STAGE_TILE

    // Epilogue. C/D layout: col = lane&15, row = (lane>>4)*4 + reg
    const int seg = n0 >> 10;
    #pragma unroll
    for (int nf = 0; nf < 2; ++nf) {
        const int cl = wc * 32 + nf * 16 + lr;
        const float bv = (mode == 3) ? 0.f : bias[n0 + cl];
        #pragma unroll
        for (int mf = 0; mf < 4; ++mf) {
            #pragma unroll
            for (int r = 0; r < 4; ++r) {
                const int row = m0 + wr * 64 + mf * 16 + kq * 4 + r;
                const float val = acc[mf][nf][r] + bv;
                if (mode == 2) {
                    const int col = (n0 & 1023) + cl;
                    float* dstf = (seg == 1) ? Ck : ((seg == 2) ? Cv : nullptr);
                    unsigned short* dstb = (seg == 0) ? Cb : ((seg == 1) ? Kb16 : Vb16);
                    if (dstf) dstf[(size_t)row * DD + col] = val;
                    dstb[(size_t)row * DD + col] = f2bf(val);
                } else if (mode == 1) {
                    Cb[(size_t)row * N + n0 + cl] = f2bf(fmaxf(val, 0.f));
                } else {   // mode 3: bf16 partial
                    Cb[(size_t)blockIdx.z * M * N + (size_t)row * N + n0 + cl] = f2bf(val);
                }
            }
        }
    }
}

// ---------------------------------------------------------------------------
// MFMA causal flash attention. Block = (128 q, h, b), 512 thr = 8 waves;
// KV-chunk 128; K[128][68], Vt[64][136], P[16][136]. Causal mask applied
// ONLY on the diagonal chunk (c == qt): for c < qt every key is <= all of
// the block's q rows, so the mask is provably a no-op there.
// ---------------------------------------------------------------------------
__global__ __launch_bounds__(512)
void attn_mfma(const unsigned short* __restrict__ Qb, const unsigned short* __restrict__ Kb,
               const unsigned short* __restrict__ Vb, unsigned short* __restrict__ ctxb)
{
    int bx = blockIdx.x, by = blockIdx.y;
    xcd_swizzle(bx, by);
    const int qt = bx;              // q-tile 0..7 (128 rows each)
    const int h  = by;
    const int b  = blockIdx.z;
    const int tid  = threadIdx.x;
    const int lane = tid & 63;
    const int w    = tid >> 6;      // 0..7
    const int lr   = lane & 15;
    const int hi   = lane >> 4;

    __shared__ unsigned short smem[128 * 68 + 64 * 136 + 8 * 16 * 136];  // 69632 B
    unsigned short* Ks = smem;                                  // [128][68] key-major
    unsigned short* Vt = smem + 128 * 68;                       // [64][136] d-major
    unsigned short* Pl = smem + 128 * 68 + 64 * 136 + w * 16 * 136; // per-wave [16][136]

    const int qg0 = qt * 128 + w * 16;   // wave's first q row

    bf16x8 qa[2];
    {
        const unsigned short* qp = Qb + ((size_t)(b * SS + qg0 + lr)) * DD + h * HD;
        qa[0] = *(const bf16x8*)(qp + hi * 8);
        qa[1] = *(const bf16x8*)(qp + 32 + hi * 8);
    }

    f32x4 accO[4];
    #pragma unroll
    for (int t = 0; t < 4; ++t) { f32x4 z = {0.f,0.f,0.f,0.f}; accO[t] = z; }
    float m_run[4], l_run[4];
    #pragma unroll
    for (int r = 0; r < 4; ++r) { m_run[r] = -INFINITY; l_run[r] = 0.f; }

    const int nch = qt + 1;     // 128-key chunks
    for (int c = 0; c < nch; ++c) {
        __syncthreads();
        const unsigned short* kb = Kb + ((size_t)(b * SS + c * 128)) * DD + h * HD;
        const unsigned short* vb = Vb + ((size_t)(b * SS + c * 128)) * DD + h * HD;
        #pragma unroll
        for (int i = 0; i < 2; ++i) {
            int e = tid + i * 512;
            int r  = e >> 3, ch = e & 7;
            bf16x8 kv = *(const bf16x8*)(kb + (size_t)r * DD + ch * 8);
            *(bf16x4*)(Ks + r * 68 + ch * 8)     = __builtin_shufflevector(kv, kv, 0,1,2,3);
            *(bf16x4*)(Ks + r * 68 + ch * 8 + 4) = __builtin_shufflevector(kv, kv, 4,5,6,7);
            int k  = e & 127, d0 = (e >> 7) * 8;
            bf16x8 vv = *(const bf16x8*)(vb + (size_t)k * DD + d0);
            #pragma unroll
            for (int j = 0; j < 8; ++j)
                Vt[(d0 + j) * 136 + k] = (unsigned short)vv[j];
        }
        __syncthreads();

        // QK^T: 8 k-tiles of 16
        f32x4 sa[8];
        #pragma unroll
        for (int t = 0; t < 8; ++t) { f32x4 z = {0.f,0.f,0.f,0.f}; sa[t] = z; }
        #pragma unroll
        for (int t = 0; t < 8; ++t) {
            #pragma unroll
            for (int s = 0; s < 2; ++s) {
                const unsigned short* bp = Ks + (t * 16 + lr) * 68 + s * 32 + hi * 8;
                bf16x4 b0 = *(const bf16x4*)bp;
                bf16x4 b1 = *(const bf16x4*)(bp + 4);
                bf16x8 bb = __builtin_shufflevector(b0, b1, 0,1,2,3,4,5,6,7);
                sa[t] = __builtin_amdgcn_mfma_f32_16x16x32_bf16(qa[s], bb, sa[t], 0, 0, 0);
            }
        }
        // scale; causal mask only on the diagonal chunk (wave-uniform branch)
        if (c == qt) {
            #pragma unroll
            for (int t = 0; t < 8; ++t) {
                #pragma unroll
                for (int r = 0; r < 4; ++r) {
                    const int kg = c * 128 + t * 16 + lr;
                    const int qg = qg0 + hi * 4 + r;
                    sa[t][r] = (kg > qg) ? -1e30f : sa[t][r] * 0.125f;
                }
            }
        } else {
            #pragma unroll
            for (int t = 0; t < 8; ++t)
                #pragma unroll
                for (int r = 0; r < 4; ++r)
                    sa[t][r] *= 0.125f;
        }
        #pragma unroll
        for (int r = 0; r < 4; ++r) {
            float mx = -INFINITY;
            #pragma unroll
            for (int t = 0; t < 8; ++t) mx = fmaxf(mx, sa[t][r]);
            mx = fmaxf(mx, __shfl_xor(mx, 1));
            mx = fmaxf(mx, __shfl_xor(mx, 2));
            mx = fmaxf(mx, __shfl_xor(mx, 4));
            mx = fmaxf(mx, __shfl_xor(mx, 8));
            const float mn = fmaxf(m_run[r], mx);
            float sum = 0.f;
            #pragma unroll
            for (int t = 0; t < 8; ++t) {
                float p = __expf(sa[t][r] - mn);
                sa[t][r] = p;
                sum += p;
            }
            sum += __shfl_xor(sum, 1);
            sum += __shfl_xor(sum, 2);
            sum += __shfl_xor(sum, 4);
            sum += __shfl_xor(sum, 8);
            const float sc = __expf(m_run[r] - mn);
            l_run[r] = l_run[r] * sc + sum;
            m_run[r] = mn;
            #pragma unroll
            for (int t = 0; t < 4; ++t) accO[t][r] *= sc;
        }
        #pragma unroll
        for (int t = 0; t < 8; ++t)
            #pragma unroll
            for (int r = 0; r < 4; ++r)
                Pl[(hi * 4 + r) * 136 + t * 16 + lr] = f2bf(sa[t][r]);

        #pragma unroll
        for (int s = 0; s < 4; ++s) {
            const unsigned short* ap = Pl + lr * 136 + s * 32 + hi * 8;
            bf16x4 a0 = *(const bf16x4*)ap;
            bf16x4 a1 = *(const bf16x4*)(ap + 4);
            bf16x8 aa = __builtin_shufflevector(a0, a1, 0,1,2,3,4,5,6,7);
            #pragma unroll
            for (int t = 0; t < 4; ++t) {
                const unsigned short* bp = Vt + (t * 16 + lr) * 136 + s * 32 + hi * 8;
                bf16x4 b0 = *(const bf16x4*)bp;
                bf16x4 b1 = *(const bf16x4*)(bp + 4);
                bf16x8 bb = __builtin_shufflevector(b0, b1, 0,1,2,3,4,5,6,7);
                accO[t] = __builtin_amdgcn_mfma_f32_16x16x32_bf16(aa, bb, accO[t], 0, 0, 0);
            }
        }
    }

    float inv[4];
    #pragma unroll
    for (int r = 0; r < 4; ++r) inv[r] = 1.f / l_run[r];

    __syncthreads();
    float* Of = (float*)smem;   // [128][68] f32 = 34816 B, overlays smem
    #pragma unroll
    for (int t = 0; t < 4; ++t)
        #pragma unroll
        for (int r = 0; r < 4; ++r)
            Of[(w * 16 + hi * 4 + r) * 68 + t * 16 + lr] = accO[t][r] * inv[r];
    __syncthreads();
    #pragma unroll
    for (int i = 0; i < 2; ++i) {
        int e = tid + i * 512;
        int r = e >> 3, ch = e & 7;
        const float* src = Of + r * 68 + ch * 8;
        float4 v0 = *(const float4*)(src);
        float4 v1 = *(const float4*)(src + 4);
        bf16x8 o;
        o[0] = (short)f2bf(v0.x); o[1] = (short)f2bf(v0.y);
        o[2] = (short)f2bf(v0.z); o[3] = (short)f2bf(v0.w);
        o[4] = (short)f2bf(v1.x); o[5] = (short)f2bf(v1.y);
        o[6] = (short)f2bf(v1.z); o[7] = (short)f2bf(v1.w);
        *(bf16x8*)(ctxb + ((size_t)(b * SS + qt * 128 + r)) * DD + h * HD + ch * 8) = o;
    }
}

// ---------------------------------------------------------------------------
// xo = LayerNorm(x + P0+P1+P2+P3 + bias) * w + b ; P = bf16 partials.
// xo may equal x (in-place) or point at d_out for the final LN.
// ---------------------------------------------------------------------------
__global__ __launch_bounds__(256)
void ln_kernel(const float* __restrict__ x, float* __restrict__ xo,
               const unsigned short* __restrict__ P,
               const float* __restrict__ bias,
               const float* __restrict__ w, const float* __restrict__ b,
               unsigned short* __restrict__ xb)
{
    const size_t PS = (size_t)BSD;   // partial stride
    const int row = blockIdx.x;
    const int t   = threadIdx.x;
    const int d0  = t * 4;
    const float* xr = x + (size_t)row * DD;
    float* xor_ = xo + (size_t)row * DD;
    unsigned short* xbr = xb + (size_t)row * DD;
    const size_t base = (size_t)row * DD + d0;

    float4 xv = *(const float4*)(xr + d0);
    float4 bv = *(const float4*)(bias + d0);
    float z[4] = {xv.x + bv.x, xv.y + bv.y, xv.z + bv.z, xv.w + bv.w};
    #pragma unroll
    for (int p = 0; p < 4; ++p) {
        ushort4 pv = *(const ushort4*)(P + base + p * PS);
        z[0] += bf2f(pv.x); z[1] += bf2f(pv.y); z[2] += bf2f(pv.z); z[3] += bf2f(pv.w);
    }
    float s = z[0] + z[1] + z[2] + z[3];
    float ss = z[0]*z[0] + z[1]*z[1] + z[2]*z[2] + z[3]*z[3];

    #pragma unroll
    for (int off = 32; off; off >>= 1) {
        s  += __shfl_down(s, off);
        ss += __shfl_down(ss, off);
    }
    __shared__ float sbuf[4], ssbuf[4];
    const int wave = t >> 6, lane = t & 63;
    if (lane == 0) { sbuf[wave] = s; ssbuf[wave] = ss; }
    __syncthreads();
    if (t == 0) {
        float S = 0.f, SSum = 0.f;
        #pragma unroll
        for (int i = 0; i < 4; ++i) { S += sbuf[i]; SSum += ssbuf[i]; }
        float mean = S * (1.f / 1024.f);
        float var  = SSum * (1.f / 1024.f) - mean * mean;
        sbuf[0]  = mean;
        ssbuf[0] = rsqrtf(var + 1e-5f);
    }
    __syncthreads();
    const float mean = sbuf[0], rstd = ssbuf[0];

    float4 wv = *(const float4*)(w + d0);
    float4 bb = *(const float4*)(b + d0);
    float o0 = (z[0] - mean) * rstd * wv.x + bb.x;
    float o1 = (z[1] - mean) * rstd * wv.y + bb.y;
    float o2 = (z[2] - mean) * rstd * wv.z + bb.z;
    float o3 = (z[3] - mean) * rstd * wv.w + bb.w;
    *(float4*)(xor_ + d0) = make_float4(o0, o1, o2, o3);
    ushort4 ob4;
    ob4.x = f2bf(o0); ob4.y = f2bf(o1); ob4.z = f2bf(o2); ob4.w = f2bf(o3);
    *(ushort4*)(xbr + d0) = ob4;
}

// ---------------------------------------------------------------------------
extern "C" void kernel_launch(void* const* d_in, const int* in_sizes, int n_in,
                              void* d_out, int out_size, void* d_ws, size_t ws_size,
                              hipStream_t stream)
{
    const float* x_in  = (const float*)d_in[0];
    const float* qkv_w = (const float*)d_in[2];
    const float* qkv_b = (const float*)d_in[3];
    const float* out_w = (const float*)d_in[4];
    const float* out_b = (const float*)d_in[5];
    const float* w1    = (const float*)d_in[6];
    const float* b1    = (const float*)d_in[7];
    const float* w2    = (const float*)d_in[8];
    const float* b2    = (const float*)d_in[9];
    const float* ln1w  = (const float*)d_in[10];
    const float* ln1b  = (const float*)d_in[11];
    const float* ln2w  = (const float*)d_in[12];
    const float* ln2b  = (const float*)d_in[13];

    float* out_x = (float*)d_out;                    // [B,S,D]
    float* out_k = out_x + (size_t)BSD;              // [L,B,S,D]
    float* out_v = out_k + (size_t)LL * BSD;         // [L,B,S,D]

    const size_t MEG = 1024 * 1024;
    float* ws = (float*)d_ws;
    float*          xbuf  = ws;                               // 2M f32 (8 MB)
    unsigned short* part16= (unsigned short*)(ws + 2 * MEG);  // 4 x 2M bf16 (16 MB)
    unsigned short* xb16  = (unsigned short*)(ws + 6 * MEG);  // 2M bf16
    unsigned short* ctxb  = (unsigned short*)(ws + 7 * MEG);  // 2M bf16
    unsigned short* hb16  = (unsigned short*)(ws + 8 * MEG);  // 8M bf16 (16 MB)
    unsigned short* qb16  = hb16;                             // aliases (disjoint lifetime)
    unsigned short* kb16  = hb16 + 2 * MEG;
    unsigned short* vb16  = hb16 + 4 * MEG;
    unsigned short* wAll  = (unsigned short*)(ws + 12 * MEG); // 96M bf16 (192 MB)

    unsigned short* qkvW = wAll;                     // 24M
    unsigned short* outW = wAll + 24 * MEG;          //  8M
    unsigned short* w1W  = wAll + 32 * MEG;          // 32M
    unsigned short* w2W  = wAll + 64 * MEG;          // 32M

    cvt_bf16<<<24 * MEG / 1024, 256, 0, stream>>>(qkv_w, qkvW);
    cvt_bf16<<< 8 * MEG / 1024, 256, 0, stream>>>(out_w, outW);
    cvt_bf16<<<32 * MEG / 1024, 256, 0, stream>>>(w1,    w1W);
    cvt_bf16<<<32 * MEG / 1024, 256, 0, stream>>>(w2,    w2W);
    cvt_x<<<BSD / 1024, 256, 0, stream>>>(x_in, xbuf, xb16);

    const int M = BB * SS;   // 2048

    for (int l = 0; l < LL; ++l) {
        const float* qb  = qkv_b + (size_t)l * 3 * DD;
        const float* ob  = out_b + (size_t)l * DD;
        const float* b1l = b1    + (size_t)l * FFD;
        const float* b2l = b2    + (size_t)l * DD;
        const unsigned short* qwl = qkvW + (size_t)l * 3 * DD * DD;
        const unsigned short* owl = outW + (size_t)l * DD * DD;
        const unsigned short* w1l = w1W  + (size_t)l * FFD * DD;
        const unsigned short* w2l = w2W  + (size_t)l * DD * FFD;
        float* kc = out_k + (size_t)l * BSD;
        float* vc = out_v + (size_t)l * BSD;

        // 1. QKV projection (full K): q/k/v bf16 + f32 caches
        gemm_bf16<<<dim3(3 * DD / 128, M / 128, 1), 512, 0, stream>>>(
            xb16, qwl, qb, nullptr, qb16, kc, vc, kb16, vb16, M, 3 * DD, DD, 2);

        // 2. MFMA causal attention -> bf16 ctx
        attn_mfma<<<dim3(SS / 128, HH, BB), 512, 0, stream>>>(qb16, kb16, vb16, ctxb);

        // 3. output projection, split-K x4 -> bf16 partials
        gemm_bf16<<<dim3(DD / 128, M / 128, 4), 512, 0, stream>>>(
            ctxb, owl, nullptr, nullptr, part16, nullptr, nullptr, nullptr, nullptr,
            M, DD, DD / 4, 3);

        // 4. x = LN(x + Σpart + ob)
        ln_kernel<<<M, 256, 0, stream>>>(xbuf, xbuf, part16, ob,
                                         ln1w + (size_t)l * DD, ln1b + (size_t)l * DD, xb16);

        // 5. h = relu(x @ w1^T + b1) -> bf16
        gemm_bf16<<<dim3(FFD / 128, M / 128, 1), 512, 0, stream>>>(
            xb16, w1l, b1l, nullptr, hb16, nullptr, nullptr, nullptr, nullptr,
            M, FFD, DD, 1);

        // 6. mlp = h @ w2^T, split-K x4 -> bf16 partials
        gemm_bf16<<<dim3(DD / 128, M / 128, 4), 512, 0, stream>>>(
            hb16, w2l, nullptr, nullptr, part16, nullptr, nullptr, nullptr, nullptr,
            M, DD, FFD / 4, 3);

        // 7. x = LN(x + Σpart + b2); last layer writes d_out directly
        float* xo = (l == LL - 1) ? out_x : xbuf;
        ln_kernel<<<M, 256, 0, stream>>>(xbuf, xo, part16, b2l,
                                         ln2w + (size_t)l * DD, ln2b + (size_t)l * DD, xb16);
    }
}